// Round 7
// baseline (395.970 us; speedup 1.0000x reference)
//
#include <hip/hip_runtime.h>
#include <stdint.h>

typedef unsigned short u16;
typedef __attribute__((ext_vector_type(8))) short short8;
typedef __attribute__((ext_vector_type(4))) short short4v;
typedef __attribute__((ext_vector_type(4))) float float4v;

union V8u { short8 v; short4v h[2]; u16 u[8]; unsigned w[4]; };

__device__ __forceinline__ u16 f2bf(float f) {
  unsigned u = __float_as_uint(f);
  u = u + 0x7FFFu + ((u >> 16) & 1u);   // round-to-nearest-even
  return (u16)(u >> 16);
}
__device__ __forceinline__ float4v fzero() {
  float4v z = {0.f, 0.f, 0.f, 0.f};
  return z;
}
__device__ __forceinline__ void gl_lds16(const u16* g, u16* l) {
  __builtin_amdgcn_global_load_lds(
      (const __attribute__((address_space(1))) void*)g,
      (__attribute__((address_space(3))) void*)l, 16, 0, 0);
}

#define MFMA16(a, b, c) __builtin_amdgcn_mfma_f32_16x16x32_bf16((a), (b), (c), 0, 0, 0)

// ---------------------------------------------------------------------------
// fp32 -> bf16 for 5 contiguous segments: X (2 segs) + wq,wk,wv. 8 elems/thr.
// ---------------------------------------------------------------------------
__global__ void conv5_f32_bf16(const float* __restrict__ X,
                               const float* __restrict__ w0,
                               const float* __restrict__ w1,
                               const float* __restrict__ w2,
                               u16* __restrict__ dst, long seg) {
  const int y = blockIdx.y;
  const float* s = (y < 2) ? (X + (long)y * seg)
                           : (y == 2 ? w0 : (y == 3 ? w1 : w2));
  u16* d = dst + (long)y * seg;
  const long i = ((long)blockIdx.x * 256 + threadIdx.x) * 8;
  if (i >= seg) return;
  float4 a = *(const float4*)&s[i];
  float4 b = *(const float4*)&s[i + 4];
  V8u o;
  o.u[0] = f2bf(a.x); o.u[1] = f2bf(a.y); o.u[2] = f2bf(a.z); o.u[3] = f2bf(a.w);
  o.u[4] = f2bf(b.x); o.u[5] = f2bf(b.y); o.u[6] = f2bf(b.z); o.u[7] = f2bf(b.w);
  *(short8*)&d[i] = o.v;
}

__global__ void conv_f32_bf16(const float* __restrict__ in, u16* __restrict__ out, long n) {
  const long i = ((long)blockIdx.x * 256 + threadIdx.x) * 8;
  if (i >= n) return;
  float4 a = *(const float4*)&in[i];
  float4 b = *(const float4*)&in[i + 4];
  V8u o;
  o.u[0] = f2bf(a.x); o.u[1] = f2bf(a.y); o.u[2] = f2bf(a.z); o.u[3] = f2bf(a.w);
  o.u[4] = f2bf(b.x); o.u[5] = f2bf(b.y); o.u[6] = f2bf(b.z); o.u[7] = f2bf(b.w);
  *(short8*)&out[i] = o.v;
}

// ---------------------------------------------------------------------------
// Balanced GEMM (FROZEN this round; ~896 TF = structure-class ceiling).
// BM=128, BN=64*NREP, BK=64, 512 thr / 8 waves (2M x 4N).
// ---------------------------------------------------------------------------
template <int NREP, bool OUTF32>
__global__ __launch_bounds__(512, 2) void gemm_bal(
    const u16* __restrict__ X, const u16* __restrict__ Wb,
    const float* __restrict__ b0, const float* __restrict__ b1,
    const float* __restrict__ b2, void* __restrict__ Out,
    int K, int cpx)
{
  constexpr int NH = NREP / 2;
  __shared__ __align__(16) u16 lds[2][(2 + NREP) * 4096];

  const int t = threadIdx.x;            // 0..511
  const int lane = t & 63;
  const int wave = t >> 6;              // 0..7
  const int quad = lane >> 4, l16 = lane & 15;
  const int wm = wave >> 2, wn = wave & 3;   // 2 x 4 wave grid

  const int bid = (int)blockIdx.x;
  const int swz = (bid & 7) * cpx + (bid >> 3);
  const int by = swz & 31;              // 32 M-tiles of 128
  const int bx = swz >> 5;              // N-tiles of 64*NREP
  const long m0 = (long)by * 128;
  const long n0 = (long)bx * (64 * NREP);

  const u16* pA[2];
  #pragma unroll
  for (int l = 0; l < 2; ++l) {
    const int d = l * 8192 + t * 16;
    const int o = d ^ ((d >> 3) & 0x70);
    pA[l] = X + (m0 + (o >> 7)) * (long)K + ((o & 127) >> 1);
  }
  const u16* pB[NREP];
  #pragma unroll
  for (int s = 0; s < NREP; ++s) {
    const int d = s * 8192 + t * 16;
    const int o = d ^ ((d >> 3) & 0x70);
    pB[s] = Wb + (n0 + (o >> 7)) * (long)K + ((o & 127) >> 1);
  }

  int offk[2];
  #pragma unroll
  for (int kk = 0; kk < 2; ++kk)
    offk[kk] = l16 * 128 + ((kk * 64 + quad * 16) ^ ((l16 & 7) << 4));

  float4v acc[4][NREP];
  #pragma unroll
  for (int i = 0; i < 4; ++i)
    #pragma unroll
    for (int j = 0; j < NREP; ++j) acc[i][j] = fzero();

  auto STAGE = [&](u16* Lb, int kt_) {
    #pragma unroll
    for (int l = 0; l < 2; ++l)
      gl_lds16(pA[l] + (long)kt_ * 64, Lb + l * 4096 + t * 8);
    #pragma unroll
    for (int s = 0; s < NREP; ++s)
      gl_lds16(pB[s] + (long)kt_ * 64, Lb + 8192 + s * 4096 + t * 8);
  };

#define SB() __builtin_amdgcn_sched_barrier(0)
#define BAR() do { asm volatile("s_barrier" ::: "memory"); SB(); } while (0)

  const int NT = K >> 6;   // 32 K-tiles of 64

  STAGE(&lds[0][0], 0);
  asm volatile("s_waitcnt vmcnt(0)" ::: "memory");
  BAR();

  for (int kt = 0; kt < NT; ++kt) {
    const int buf = kt & 1;
    const int nkt = (kt + 1 < NT) ? kt + 1 : NT - 1;
    const char* Ab = (const char*)&lds[buf][0] + wm * 8192;
    const char* Bb = (const char*)&lds[buf][8192] + wn * (16 * NREP) * 128;

    short8 a[4][2], b[NREP][2];

    STAGE(&lds[buf ^ 1][0], nkt);

    #pragma unroll
    for (int i = 0; i < 4; ++i)
      a[i][0] = *(const short8*)(Ab + i * 2048 + offk[0]);
    #pragma unroll
    for (int j = 0; j < NH; ++j)
      b[j][0] = *(const short8*)(Bb + j * 2048 + offk[0]);
    #pragma unroll
    for (int j = NH; j < NREP; ++j)
      b[j][0] = *(const short8*)(Bb + j * 2048 + offk[0]);
    #pragma unroll
    for (int i = 0; i < 4; ++i)
      a[i][1] = *(const short8*)(Ab + i * 2048 + offk[1]);
    SB();

    __builtin_amdgcn_s_setprio(1);
    #pragma unroll
    for (int i = 0; i < 4; ++i)
      #pragma unroll
      for (int j = 0; j < NH; ++j)
        acc[i][j] = MFMA16(a[i][0], b[j][0], acc[i][j]);
    __builtin_amdgcn_s_setprio(0);
    SB();

    #pragma unroll
    for (int j = 0; j < NH; ++j)
      b[j][1] = *(const short8*)(Bb + j * 2048 + offk[1]);
    SB();

    __builtin_amdgcn_s_setprio(1);
    #pragma unroll
    for (int i = 0; i < 4; ++i)
      #pragma unroll
      for (int j = NH; j < NREP; ++j)
        acc[i][j] = MFMA16(a[i][0], b[j][0], acc[i][j]);
    __builtin_amdgcn_s_setprio(0);
    SB();

    #pragma unroll
    for (int j = NH; j < NREP; ++j)
      b[j][1] = *(const short8*)(Bb + j * 2048 + offk[1]);
    SB();

    __builtin_amdgcn_s_setprio(1);
    #pragma unroll
    for (int i = 0; i < 4; ++i)
      #pragma unroll
      for (int j = 0; j < NH; ++j)
        acc[i][j] = MFMA16(a[i][1], b[j][1], acc[i][j]);
    __builtin_amdgcn_s_setprio(0);
    SB();

    __builtin_amdgcn_s_setprio(1);
    #pragma unroll
    for (int i = 0; i < 4; ++i)
      #pragma unroll
      for (int j = NH; j < NREP; ++j)
        acc[i][j] = MFMA16(a[i][1], b[j][1], acc[i][j]);
    __builtin_amdgcn_s_setprio(0);

    asm volatile("s_waitcnt vmcnt(0)" ::: "memory");
    BAR();
  }

#undef SB
#undef BAR

  #pragma unroll
  for (int j = 0; j < NREP; ++j) {
    const int cg = (int)n0 + wn * (16 * NREP) + j * 16 + l16;
    const int z = cg >> 11, col = cg & 2047;
    const float* Bp = (z == 0) ? b0 : (z == 1 ? b1 : b2);
    const float bvv = Bp[col];
    #pragma unroll
    for (int i = 0; i < 4; ++i) {
      const long r0 = m0 + wm * 64 + i * 16 + quad * 4;
      #pragma unroll
      for (int r = 0; r < 4; ++r) {
        const long off = (long)z * (4096L * 2048) + (r0 + r) * 2048 + col;
        const float v = acc[i][j][r] + bvv;
        if (OUTF32) ((float*)Out)[off] = v;
        else        ((u16*)Out)[off] = f2bf(v);
      }
    }
  }
}

// ---------------------------------------------------------------------------
// Causal flash attention — TLP + bank-conflict round.
// 128 thr / 2 waves per block, 64 Q rows per block (32/wave, 2 groups of 16;
// wave-level math IDENTICAL to the verified 256-thr version).
// grid = 1024 = 32 bh x 32 Q-tiles -> 4 blocks/CU (LDS 39.4 KB), 8 waves/CU
// = 2 waves/SIMD (was 1: every latency in the serial QK^T->softmax->PV chain
// was exposed; nothing was busy in the counters).
// Balance: co-resident blocks (linear ids +256k) get tiles {s,15-s,16+s,31-s}
// -> per-CU KV-tile-unit sum = 68 for every s (under round-robin dispatch).
// bh = L&31 -> all 32 blocks of a head on one XCD (K/V L2 locality, T1).
// Conflict fixes: Ks pad 136->132 (kf ds_read_b128 4-way -> 2-way=free);
// Ps row stride 32->40 (pf ds_read_b128 8-way -> 2-way=free).
// In-place Ctx-over-Qw safe: each block reads only its own 64 Q rows
// (upfront) / head-cols before writing them.
// ---------------------------------------------------------------------------
#define S_LEN 2048
#define HID   2048
#define HD    128

__global__ __launch_bounds__(128, 2) void attn_fwd(
    const u16* __restrict__ Q, const u16* __restrict__ K,
    const u16* __restrict__ V, u16* __restrict__ Ctx)
{
  __shared__ u16 Ks[2][32 * 132];      // K rows natural, pad 4 (2-way free)
  __shared__ unsigned Vt[2][128 * 17]; // Vt[c][r/2] = V[2r'][c] | V[2r'+1][c]<<16
  __shared__ u16 Ps[2][2][16 * 40];    // [wave][group][row][40] (2-way free)

  const int t = threadIdx.x;           // 0..127
  const int lane = t & 63, wave = t >> 6;   // wave 0..1
  const int quad = lane >> 4, l16 = lane & 15;

  const int L = (int)blockIdx.x;       // 0..1023
  const int bh = L & 31;               // same-bh blocks -> same XCD (L%8 inv.)
  const int v = L >> 5;                // 0..31
  const int s8 = v & 7, k4 = v >> 3;
  const int tt = (k4 == 0) ? s8 : (k4 == 1) ? (15 - s8)
               : (k4 == 2) ? (16 + s8) : (31 - s8);   // bijective, CU-balanced
  const int b = bh >> 4, h = bh & 15;
  const int qb = tt * 64;

  const long base = (long)b * S_LEN * HID + (long)h * HD;
  const u16* Qp = Q + base;
  const u16* Kp = K + base;
  const u16* Vp = V + base;
  u16* Cp = Ctx + base;

  const int sr2 = t >> 4;          // 0..7: row-pairs sr2 and sr2+8
  const int sc8 = (t & 15) * 8;    // feature col base
  const int wqb = qb + wave * 32;  // wave's first Q row

  // Q fragments for both groups (A-layout: m=lane&15, k=quad*8+j)
  short8 qf[2][4];
  #pragma unroll
  for (int g = 0; g < 2; ++g) {
    const long qr = wqb + g * 16 + l16;
    #pragma unroll
    for (int kk = 0; kk < 4; ++kk)
      qf[g][kk] = *(const short8*)&Qp[qr * HID + kk * 32 + quad * 8];
  }

  short8 onesv;
  {
    V8u ou;
    #pragma unroll
    for (int j = 0; j < 8; ++j) ou.u[j] = 0x3F80;   // bf16 1.0
    onesv = ou.v;
  }
  const float SC = 0.08838834764831845f * 1.4426950408889634f; // scale*log2e

  float4v o[2][9];                 // per group: [0..7] d-groups, [8] row-sum
  #pragma unroll
  for (int g = 0; g < 2; ++g)
    #pragma unroll
    for (int i = 0; i < 9; ++i) o[g][i] = fzero();

  // 128-thread staging: 4 K rows + 4 V rows per thread
  short8 kr[4], vv[4];
  auto LOADKV = [&](int row0) {
    const long g0 = (long)(row0 + 2 * sr2) * HID + sc8;
    kr[0] = *(const short8*)&Kp[g0];
    kr[1] = *(const short8*)&Kp[g0 + HID];
    kr[2] = *(const short8*)&Kp[g0 + 16 * HID];
    kr[3] = *(const short8*)&Kp[g0 + 17 * HID];
    vv[0] = *(const short8*)&Vp[g0];
    vv[1] = *(const short8*)&Vp[g0 + HID];
    vv[2] = *(const short8*)&Vp[g0 + 16 * HID];
    vv[3] = *(const short8*)&Vp[g0 + 17 * HID];
  };
  auto COMMIT = [&](int p) {
    *(short8*)&Ks[p][(2 * sr2) * 132 + sc8]      = kr[0];
    *(short8*)&Ks[p][(2 * sr2 + 1) * 132 + sc8]  = kr[1];
    *(short8*)&Ks[p][(2 * sr2 + 16) * 132 + sc8] = kr[2];
    *(short8*)&Ks[p][(2 * sr2 + 17) * 132 + sc8] = kr[3];
    V8u a0, a1, a2, a3;
    a0.v = vv[0]; a1.v = vv[1]; a2.v = vv[2]; a3.v = vv[3];
    #pragma unroll
    for (int j = 0; j < 8; ++j) {
      Vt[p][(sc8 + j) * 17 + sr2]     = (unsigned)a0.u[j] | ((unsigned)a1.u[j] << 16);
      Vt[p][(sc8 + j) * 17 + sr2 + 8] = (unsigned)a2.u[j] | ((unsigned)a3.u[j] << 16);
    }
  };

  LOADKV(0);
  COMMIT(0);
  __syncthreads();

  const int T = (qb + 64) >> 5;    // number of 32-row KV tiles = 2*tt+2
  for (int ti = 0; ti < T; ++ti) {
    const int kv0 = ti << 5;
    const int p = ti & 1;

    const bool more = (ti + 1 < T);
    if (more) LOADKV(kv0 + 32);

    // wave-uniform activity (kv0, wqb both 32-aligned)
    if (kv0 <= wqb) {
      // ---- S = Q . K^T for both groups (kf read once, used twice) ----
      float4v s[2][2];
      #pragma unroll
      for (int g = 0; g < 2; ++g) { s[g][0] = fzero(); s[g][1] = fzero(); }
      #pragma unroll
      for (int ni = 0; ni < 2; ++ni)
        #pragma unroll
        for (int kk = 0; kk < 4; ++kk) {
          short8 kf = *(const short8*)&Ks[p][(ni * 16 + l16) * 132 + kk * 32 + quad * 8];
          s[0][ni] = MFMA16(qf[0][kk], kf, s[0][ni]);
          s[1][ni] = MFMA16(qf[1][kk], kf, s[1][ni]);
        }

      // ---- fixed-scale exp + causal mask + P round-trip per group ----
      #pragma unroll
      for (int g = 0; g < 2; ++g) {
        const int qrow0 = wqb + g * 16 + quad * 4;
        #pragma unroll
        for (int r = 0; r < 4; ++r) {
          float s0 = fminf(s[g][0][r] * SC, 80.f);
          float s1 = fminf(s[g][1][r] * SC, 80.f);
          if (kv0 + l16 > qrow0 + r)      s0 = -1e30f;
          if (kv0 + 16 + l16 > qrow0 + r) s1 = -1e30f;
          Ps[wave][g][(quad * 4 + r) * 40 + l16]      = f2bf(__builtin_amdgcn_exp2f(s0));
          Ps[wave][g][(quad * 4 + r) * 40 + 16 + l16] = f2bf(__builtin_amdgcn_exp2f(s1));
        }
      }
      __threadfence_block();
      short8 pf0 = *(const short8*)&Ps[wave][0][l16 * 40 + quad * 8];
      short8 pf1 = *(const short8*)&Ps[wave][1][l16 * 40 + quad * 8];

      // ---- O += P . V (vf read once, used twice) ; ones row-sum ----
      #pragma unroll
      for (int dt = 0; dt < 8; ++dt) {
        const unsigned* vp = &Vt[p][(dt * 16 + l16) * 17 + quad * 4];
        V8u vf;
        vf.w[0] = vp[0]; vf.w[1] = vp[1]; vf.w[2] = vp[2]; vf.w[3] = vp[3];
        o[0][dt] = MFMA16(pf0, vf.v, o[0][dt]);
        o[1][dt] = MFMA16(pf1, vf.v, o[1][dt]);
      }
      o[0][8] = MFMA16(pf0, onesv, o[0][8]);
      o[1][8] = MFMA16(pf1, onesv, o[1][8]);
    }

    if (more) COMMIT(1 - p);
    __syncthreads();
  }

  // ---- epilogue: O / L -> ctx (merged-head layout [B*S][H]) ----
  #pragma unroll
  for (int g = 0; g < 2; ++g)
    #pragma unroll
    for (int r = 0; r < 4; ++r) {
      const float inv = 1.0f / o[g][8][r];
      const long qr = wqb + g * 16 + quad * 4 + r;
      #pragma unroll
      for (int dt = 0; dt < 8; ++dt)
        Cp[qr * HID + dt * 16 + l16] = f2bf(o[g][dt][r] * inv);
    }
}

// ---------------------------------------------------------------------------
extern "C" void kernel_launch(void* const* d_in, const int* in_sizes, int n_in,
                              void* d_out, int out_size, void* d_ws, size_t ws_size,
                              hipStream_t stream) {
  const float* X  = (const float*)d_in[0];
  const float* wq = (const float*)d_in[1];
  const float* bq = (const float*)d_in[2];
  const float* wk = (const float*)d_in[3];
  const float* bk = (const float*)d_in[4];
  const float* wv = (const float*)d_in[5];
  const float* bv = (const float*)d_in[6];
  const float* wo = (const float*)d_in[7];
  const float* bo = (const float*)d_in[8];
  float* out = (float*)d_out;

  const long HSZ = 4096L * 2048;   // B*S x H
  const long WSZ = 2048L * 2048;
  // ws (bf16 elems): Qw Kw Vw (3x16.8MB) + Xb (16.8MB) + W0..W2 (3x8.4MB)
  u16* Qw = (u16*)d_ws;
  u16* Kw = Qw + HSZ;
  u16* Vw = Kw + HSZ;
  u16* Xb = Vw + HSZ;
  u16* Wb = Xb + HSZ;              // W0,W1,W2 contiguous after Xb
  u16* W0 = Wb;

  dim3 blk(256);
  // one fused conversion: X (2 segs) + wq + wk + wv into Xb..W2 (contiguous)
  conv5_f32_bf16<<<dim3((int)(WSZ / 2048), 5), blk, 0, stream>>>(X, wq, wk, wv, Xb, WSZ);

  // fused Q/K/V projections: M=4096, N=6144, K=2048 (frozen).
  gemm_bal<6, false><<<dim3(512), dim3(512), 0, stream>>>(
      Xb, Wb, bq, bk, bv, Qw, 2048, 64);

  // causal flash attention: 1024 blocks x 128 thr (4 blk/CU, 2 waves/SIMD),
  // CU-balanced tile permutation + XCD-local heads; ctx in-place over Qw.
  attn_fwd<<<dim3(1024), dim3(128), 0, stream>>>(Qw, Kw, Vw, Qw);

  // output projection (fp32 out): BN=256 -> grid 256 = exactly 1 block/CU.
  conv_f32_bf16<<<(int)(WSZ / 2048), blk, 0, stream>>>(wo, W0, WSZ);
  gemm_bal<4, true><<<dim3(256), dim3(512), 0, stream>>>(
      Qw, W0, bo, bo, bo, out, 2048, 32);
}

// Round 8
// 394.391 us; speedup vs baseline: 1.0040x; 1.0040x over previous
//
#include <hip/hip_runtime.h>
#include <stdint.h>

typedef unsigned short u16;
typedef __attribute__((ext_vector_type(8))) short short8;
typedef __attribute__((ext_vector_type(4))) short short4v;
typedef __attribute__((ext_vector_type(4))) float float4v;

union V8u { short8 v; short4v h[2]; u16 u[8]; unsigned w[4]; };

__device__ __forceinline__ u16 f2bf(float f) {
  unsigned u = __float_as_uint(f);
  u = u + 0x7FFFu + ((u >> 16) & 1u);   // round-to-nearest-even
  return (u16)(u >> 16);
}
__device__ __forceinline__ float4v fzero() {
  float4v z = {0.f, 0.f, 0.f, 0.f};
  return z;
}
__device__ __forceinline__ void gl_lds16(const u16* g, u16* l) {
  __builtin_amdgcn_global_load_lds(
      (const __attribute__((address_space(1))) void*)g,
      (__attribute__((address_space(3))) void*)l, 16, 0, 0);
}

#define MFMA16(a, b, c) __builtin_amdgcn_mfma_f32_16x16x32_bf16((a), (b), (c), 0, 0, 0)

// ---------------------------------------------------------------------------
// fp32 -> bf16 for 5 contiguous segments: X (2 segs) + wq,wk,wv. 8 elems/thr.
// ---------------------------------------------------------------------------
__global__ void conv5_f32_bf16(const float* __restrict__ X,
                               const float* __restrict__ w0,
                               const float* __restrict__ w1,
                               const float* __restrict__ w2,
                               u16* __restrict__ dst, long seg) {
  const int y = blockIdx.y;
  const float* s = (y < 2) ? (X + (long)y * seg)
                           : (y == 2 ? w0 : (y == 3 ? w1 : w2));
  u16* d = dst + (long)y * seg;
  const long i = ((long)blockIdx.x * 256 + threadIdx.x) * 8;
  if (i >= seg) return;
  float4 a = *(const float4*)&s[i];
  float4 b = *(const float4*)&s[i + 4];
  V8u o;
  o.u[0] = f2bf(a.x); o.u[1] = f2bf(a.y); o.u[2] = f2bf(a.z); o.u[3] = f2bf(a.w);
  o.u[4] = f2bf(b.x); o.u[5] = f2bf(b.y); o.u[6] = f2bf(b.z); o.u[7] = f2bf(b.w);
  *(short8*)&d[i] = o.v;
}

__global__ void conv_f32_bf16(const float* __restrict__ in, u16* __restrict__ out, long n) {
  const long i = ((long)blockIdx.x * 256 + threadIdx.x) * 8;
  if (i >= n) return;
  float4 a = *(const float4*)&in[i];
  float4 b = *(const float4*)&in[i + 4];
  V8u o;
  o.u[0] = f2bf(a.x); o.u[1] = f2bf(a.y); o.u[2] = f2bf(a.z); o.u[3] = f2bf(a.w);
  o.u[4] = f2bf(b.x); o.u[5] = f2bf(b.y); o.u[6] = f2bf(b.z); o.u[7] = f2bf(b.w);
  *(short8*)&out[i] = o.v;
}

// ---------------------------------------------------------------------------
// Balanced GEMM, m201-faithful FINE-PHASE schedule.
// BM=128, BN=64*NREP, BK=64, 512 thr / 8 waves (2M x 4N).
//   QKV: NREP=6 (BN=384): grid 512 = exactly 2 balanced rounds.
//   OP:  NREP=4 (BN=256): grid 256 = exactly 1 block/CU.
// LDS: lds[2][A(2 segs) | B(NREP segs)], seg = 64 rows x 64 k = 8 KiB.
//
// 4 phases per K-tile, each {reads (+stage) -> s_barrier -> lgkmcnt(0) ->
// setprio(1) -> MFMA cluster -> setprio(0) -> s_barrier}:
//   ph0: A.k0 x Blow.k0   | stage Bh(kt+1) -> other buf | vmcnt(N+2) @end
//   ph1: A.k0 x Bhigh.k0
//   ph2: A.k1 x Blow.k1
//   ph3: A.k1 x Bhigh.k1  | stage A+Bl(kt+2) -> CURRENT buf (regions dead
//        after ph2: every wave's lgkmcnt(0) precedes its MFMAs precedes the
//        ph2 closing barrier) | vmcnt(N+2) @end
// Counted-vmcnt ledger (issue order ...,A+Bl(kt+1)@ph3(kt-1), Bh(kt+1)@ph0(kt),
// A+Bl(kt+2)@ph3(kt),...): ph0-end outstanding = 3+5+3 -> vmcnt(8) retires
// Bh(kt) (needed ph1); ph3-end outstanding = 5+3+5 -> vmcnt(8) retires
// A+Bl(kt+1) (needed next ph0). Every load waits >=4 phases (~1900cyc) after
// issue; queue NEVER drains (T4). NREP=4: counts 2/4 -> vmcnt(6), same proof.
// T2 swizzle (0 conflicts, verified R1-R7); T5 setprio; T1 XCD swizzle.
// ---------------------------------------------------------------------------
template <int NREP, bool OUTF32>
__global__ __launch_bounds__(512, 2) void gemm_bal(
    const u16* __restrict__ X, const u16* __restrict__ Wb,
    const float* __restrict__ b0, const float* __restrict__ b1,
    const float* __restrict__ b2, void* __restrict__ Out,
    int K, int cpx)
{
  constexpr int NH = NREP / 2;
  __shared__ __align__(16) u16 lds[2][(2 + NREP) * 4096];

  const int t = threadIdx.x;            // 0..511
  const int lane = t & 63;
  const int wave = t >> 6;              // 0..7
  const int quad = lane >> 4, l16 = lane & 15;
  const int wm = wave >> 2, wn = wave & 3;   // 2 x 4 wave grid

  const int bid = (int)blockIdx.x;
  const int swz = (bid & 7) * cpx + (bid >> 3);
  const int by = swz & 31;              // 32 M-tiles of 128
  const int bx = swz >> 5;              // N-tiles of 64*NREP
  const long m0 = (long)by * 128;
  const long n0 = (long)bx * (64 * NREP);

  // staging sources (inverse-swizzled): dest d = seg*8192 + t*16 bytes,
  // logical o = d ^ ((d>>3)&0x70); row = o>>7, col elem = (o&127)>>1.
  const u16* pA[2];
  #pragma unroll
  for (int l = 0; l < 2; ++l) {
    const int d = l * 8192 + t * 16;
    const int o = d ^ ((d >> 3) & 0x70);
    pA[l] = X + (m0 + (o >> 7)) * (long)K + ((o & 127) >> 1);
  }
  const u16* pB[NREP];
  #pragma unroll
  for (int s = 0; s < NREP; ++s) {
    const int d = s * 8192 + t * 16;
    const int o = d ^ ((d >> 3) & 0x70);
    pB[s] = Wb + (n0 + (o >> 7)) * (long)K + ((o & 127) >> 1);
  }

  // per-lane swizzled ds_read byte offsets (row base added separately)
  int offk[2];
  #pragma unroll
  for (int kk = 0; kk < 2; ++kk)
    offk[kk] = l16 * 128 + ((kk * 64 + quad * 16) ^ ((l16 & 7) << 4));

  float4v acc[4][NREP];
  #pragma unroll
  for (int i = 0; i < 4; ++i)
    #pragma unroll
    for (int j = 0; j < NREP; ++j) acc[i][j] = fzero();

  auto STG_ABL = [&](int bs, int kt_) {   // A (2 segs) + B-low (NH segs)
    #pragma unroll
    for (int l = 0; l < 2; ++l)
      gl_lds16(pA[l] + (long)kt_ * 64, &lds[bs][l * 4096 + t * 8]);
    #pragma unroll
    for (int s = 0; s < NH; ++s)
      gl_lds16(pB[s] + (long)kt_ * 64, &lds[bs][(2 + s) * 4096 + t * 8]);
  };
  auto STG_BH = [&](int bs, int kt_) {    // B-high (NREP-NH segs)
    #pragma unroll
    for (int s = NH; s < NREP; ++s)
      gl_lds16(pB[s] + (long)kt_ * 64, &lds[bs][(2 + s) * 4096 + t * 8]);
  };

#define VMW() do { if constexpr (NREP == 6)                                    \
      asm volatile("s_waitcnt vmcnt(8)" ::: "memory");                         \
    else                                                                       \
      asm volatile("s_waitcnt vmcnt(6)" ::: "memory"); } while (0)
#define LGKM() do { asm volatile("s_waitcnt lgkmcnt(0)" ::: "memory");         \
                    __builtin_amdgcn_sched_barrier(0); } while (0)
#define BAR() do { asm volatile("s_barrier" ::: "memory");                     \
                   __builtin_amdgcn_sched_barrier(0); } while (0)

  const int NT = K >> 6;   // 32 K-tiles of 64

  // prologue: A+Bl(0), Bh(0) -> buf0; A+Bl(1) -> buf1; retire A+Bl(0)
  STG_ABL(0, 0);
  STG_BH(0, 0);
  STG_ABL(1, 1);
  VMW();
  BAR();

  for (int kt = 0; kt < NT; ++kt) {
    const int cur = kt & 1, nb = cur ^ 1;
    const int k1 = (kt + 1 < NT) ? kt + 1 : NT - 1;   // tail: dummy stages
    const int k2 = (kt + 2 < NT) ? kt + 2 : NT - 1;
    const char* Ab = (const char*)&lds[cur][0] + wm * 8192;
    const char* Bb = (const char*)&lds[cur][2 * 4096] + wn * (16 * NREP) * 128;

    short8 a[4][2], b[NREP][2];

    // ------------- phase 0: A.k0 x Blow.k0 | stage Bh(kt+1) -------------
    STG_BH(nb, k1);
    #pragma unroll
    for (int i = 0; i < 4; ++i)
      a[i][0] = *(const short8*)(Ab + i * 2048 + offk[0]);
    #pragma unroll
    for (int j = 0; j < NH; ++j)
      b[j][0] = *(const short8*)(Bb + j * 2048 + offk[0]);
    BAR();
    LGKM();
    __builtin_amdgcn_s_setprio(1);
    #pragma unroll
    for (int i = 0; i < 4; ++i)
      #pragma unroll
      for (int j = 0; j < NH; ++j)
        acc[i][j] = MFMA16(a[i][0], b[j][0], acc[i][j]);
    __builtin_amdgcn_s_setprio(0);
    VMW();                 // retires Bh(kt) -> valid for ph1 after this BAR
    BAR();

    // ------------- phase 1: A.k0 x Bhigh.k0 -------------
    #pragma unroll
    for (int j = NH; j < NREP; ++j)
      b[j][0] = *(const short8*)(Bb + j * 2048 + offk[0]);
    BAR();
    LGKM();
    __builtin_amdgcn_s_setprio(1);
    #pragma unroll
    for (int i = 0; i < 4; ++i)
      #pragma unroll
      for (int j = NH; j < NREP; ++j)
        acc[i][j] = MFMA16(a[i][0], b[j][0], acc[i][j]);
    __builtin_amdgcn_s_setprio(0);
    BAR();

    // ------------- phase 2: A.k1 x Blow.k1 -------------
    #pragma unroll
    for (int i = 0; i < 4; ++i)
      a[i][1] = *(const short8*)(Ab + i * 2048 + offk[1]);
    #pragma unroll
    for (int j = 0; j < NH; ++j)
      b[j][1] = *(const short8*)(Bb + j * 2048 + offk[1]);
    BAR();
    LGKM();
    __builtin_amdgcn_s_setprio(1);
    #pragma unroll
    for (int i = 0; i < 4; ++i)
      #pragma unroll
      for (int j = 0; j < NH; ++j)
        acc[i][j] = MFMA16(a[i][1], b[j][1], acc[i][j]);
    __builtin_amdgcn_s_setprio(0);
    BAR();

    // ------------- phase 3: A.k1 x Bhigh.k1 | stage A+Bl(kt+2) -------------
    STG_ABL(cur, k2);      // A/Bl regions of CURRENT buf dead after ph2
    #pragma unroll
    for (int j = NH; j < NREP; ++j)
      b[j][1] = *(const short8*)(Bb + j * 2048 + offk[1]);
    BAR();
    LGKM();
    __builtin_amdgcn_s_setprio(1);
    #pragma unroll
    for (int i = 0; i < 4; ++i)
      #pragma unroll
      for (int j = NH; j < NREP; ++j)
        acc[i][j] = MFMA16(a[i][1], b[j][1], acc[i][j]);
    __builtin_amdgcn_s_setprio(0);
    VMW();                 // retires A+Bl(kt+1) -> valid for next ph0
    BAR();
  }
  asm volatile("s_waitcnt vmcnt(0)" ::: "memory");   // drain tail dummies

#undef VMW
#undef LGKM
#undef BAR

  // epilogue: bias + store; segment z = col>>11 (Q/K/V or single for OP)
  #pragma unroll
  for (int j = 0; j < NREP; ++j) {
    const int cg = (int)n0 + wn * (16 * NREP) + j * 16 + l16;
    const int z = cg >> 11, col = cg & 2047;
    const float* Bp = (z == 0) ? b0 : (z == 1 ? b1 : b2);
    const float bvv = Bp[col];
    #pragma unroll
    for (int i = 0; i < 4; ++i) {
      const long r0 = m0 + wm * 64 + i * 16 + quad * 4;
      #pragma unroll
      for (int r = 0; r < 4; ++r) {
        const long off = (long)z * (4096L * 2048) + (r0 + r) * 2048 + col;
        const float v = acc[i][j][r] + bvv;
        if (OUTF32) ((float*)Out)[off] = v;
        else        ((u16*)Out)[off] = f2bf(v);
      }
    }
  }
}

// ---------------------------------------------------------------------------
// Causal flash attention (REVERTED to the measured-better R5-proposal form:
// the R6 TLP/conflict rework was +3.5us). Fixed-scale softmax + ones-column
// row-sum, 32 Q rows per wave / 128 Q rows per pass.
// BALANCED: grid.x = 8; block x processes Q-tile (15-x) [heavy] then (x)
// [light] -> uniform 17 KV-tile-units per block. In-place Ctx-over-Qw safe:
// heavy passes write rows 1024..2047, light passes read rows 0..1023.
// ---------------------------------------------------------------------------
#define S_LEN 2048
#define HID   2048
#define HD    128

__global__ __launch_bounds__(256, 2) void attn_fwd(
    const u16* __restrict__ Q, const u16* __restrict__ K,
    const u16* __restrict__ V, u16* __restrict__ Ctx)
{
  __shared__ u16 Ks[2][32 * 136];      // K rows natural, pad 8
  __shared__ unsigned Vt[2][128 * 17]; // Vt[c][r/2] = V[2r'][c] | V[2r'+1][c]<<16
  __shared__ u16 Ps[4 * 2 * 512];      // per-wave, per-group P round-trip

  const int t = threadIdx.x;
  const int lane = t & 63, wave = t >> 6;
  const int quad = lane >> 4, l16 = lane & 15;
  const int b = blockIdx.y >> 4, h = blockIdx.y & 15;

  const long base = (long)b * S_LEN * HID + (long)h * HD;
  const u16* Qp = Q + base;
  const u16* Kp = K + base;
  const u16* Vp = V + base;
  u16* Cp = Ctx + base;

  const int sr2 = t >> 4;          // 0..15: rows 2*sr2, 2*sr2+1 of the tile
  const int sc8 = (t & 15) * 8;    // feature col base

  short8 onesv;
  {
    V8u ou;
    #pragma unroll
    for (int j = 0; j < 8; ++j) ou.u[j] = 0x3F80;   // bf16 1.0
    onesv = ou.v;
  }
  const float SC = 0.08838834764831845f * 1.4426950408889634f; // scale*log2e

  for (int pass = 0; pass < 2; ++pass) {
    const int qb = (pass ? (int)blockIdx.x : 15 - (int)blockIdx.x) * 128;
    const int wqb = qb + wave * 32;  // wave's first Q row

    // Q fragments for both groups (A-layout: m=lane&15, k=quad*8+j)
    short8 qf[2][4];
    #pragma unroll
    for (int g = 0; g < 2; ++g) {
      const long qr = wqb + g * 16 + l16;
      #pragma unroll
      for (int kk = 0; kk < 4; ++kk)
        qf[g][kk] = *(const short8*)&Qp[qr * HID + kk * 32 + quad * 8];
    }

    float4v o[2][9];                 // per group: [0..7] d-groups, [8] row-sum
    #pragma unroll
    for (int g = 0; g < 2; ++g)
      #pragma unroll
      for (int i = 0; i < 9; ++i) o[g][i] = fzero();

    // prefetch tile 0 into regs, commit to buf 0
    short8 kr0, kr1, vv0, vv1;
    {
      const long g = (long)(2 * sr2) * HID + sc8;
      kr0 = *(const short8*)&Kp[g];
      kr1 = *(const short8*)&Kp[g + HID];
      vv0 = *(const short8*)&Vp[g];
      vv1 = *(const short8*)&Vp[g + HID];
    }
    {
      *(short8*)&Ks[0][(2 * sr2) * 136 + sc8]     = kr0;
      *(short8*)&Ks[0][(2 * sr2 + 1) * 136 + sc8] = kr1;
      V8u a, c; a.v = vv0; c.v = vv1;
      #pragma unroll
      for (int j = 0; j < 8; ++j)
        Vt[0][(sc8 + j) * 17 + sr2] = (unsigned)a.u[j] | ((unsigned)c.u[j] << 16);
    }
    __syncthreads();

    const int T = (qb + 128) >> 5;   // number of 32-row KV tiles
    for (int ti = 0; ti < T; ++ti) {
      const int kv0 = ti << 5;
      const int p = ti & 1;

      const bool more = (ti + 1 < T);
      if (more) {
        const long g = (long)(kv0 + 32 + 2 * sr2) * HID + sc8;
        kr0 = *(const short8*)&Kp[g];
        kr1 = *(const short8*)&Kp[g + HID];
        vv0 = *(const short8*)&Vp[g];
        vv1 = *(const short8*)&Vp[g + HID];
      }

      // wave-uniform activity: both groups share it (kv0, wqb 32-aligned)
      if (kv0 <= wqb) {
        // ---- S = Q . K^T for both groups (kf read once, used twice) ----
        float4v s[2][2];
        #pragma unroll
        for (int g = 0; g < 2; ++g) { s[g][0] = fzero(); s[g][1] = fzero(); }
        #pragma unroll
        for (int ni = 0; ni < 2; ++ni)
          #pragma unroll
          for (int kk = 0; kk < 4; ++kk) {
            short8 kf = *(const short8*)&Ks[p][(ni * 16 + l16) * 136 + kk * 32 + quad * 8];
            s[0][ni] = MFMA16(qf[0][kk], kf, s[0][ni]);
            s[1][ni] = MFMA16(qf[1][kk], kf, s[1][ni]);
          }

        // ---- fixed-scale exp + causal mask + P round-trip per group ----
        const int pb = wave * 1024;
        #pragma unroll
        for (int g = 0; g < 2; ++g) {
          const int qrow0 = wqb + g * 16 + quad * 4;
          #pragma unroll
          for (int r = 0; r < 4; ++r) {
            float s0 = fminf(s[g][0][r] * SC, 80.f);
            float s1 = fminf(s[g][1][r] * SC, 80.f);
            if (kv0 + l16 > qrow0 + r)      s0 = -1e30f;
            if (kv0 + 16 + l16 > qrow0 + r) s1 = -1e30f;
            Ps[pb + g * 512 + (quad * 4 + r) * 32 + l16]      = f2bf(__builtin_amdgcn_exp2f(s0));
            Ps[pb + g * 512 + (quad * 4 + r) * 32 + 16 + l16] = f2bf(__builtin_amdgcn_exp2f(s1));
          }
        }
        __threadfence_block();
        short8 pf0 = *(const short8*)&Ps[pb + l16 * 32 + quad * 8];
        short8 pf1 = *(const short8*)&Ps[pb + 512 + l16 * 32 + quad * 8];

        // ---- O += P . V (vf read once, used twice) ; ones row-sum ----
        #pragma unroll
        for (int dt = 0; dt < 8; ++dt) {
          const unsigned* vp = &Vt[p][(dt * 16 + l16) * 17 + quad * 4];
          V8u vf;
          vf.w[0] = vp[0]; vf.w[1] = vp[1]; vf.w[2] = vp[2]; vf.w[3] = vp[3];
          o[0][dt] = MFMA16(pf0, vf.v, o[0][dt]);
          o[1][dt] = MFMA16(pf1, vf.v, o[1][dt]);
        }
        o[0][8] = MFMA16(pf0, onesv, o[0][8]);
        o[1][8] = MFMA16(pf1, onesv, o[1][8]);
      }

      if (more) {
        *(short8*)&Ks[1 - p][(2 * sr2) * 136 + sc8]     = kr0;
        *(short8*)&Ks[1 - p][(2 * sr2 + 1) * 136 + sc8] = kr1;
        V8u a, c; a.v = vv0; c.v = vv1;
        #pragma unroll
        for (int j = 0; j < 8; ++j)
          Vt[1 - p][(sc8 + j) * 17 + sr2] = (unsigned)a.u[j] | ((unsigned)c.u[j] << 16);
      }
      __syncthreads();
    }

    // ---- epilogue: O / L -> ctx (merged-head layout [B*S][H]) ----
    #pragma unroll
    for (int g = 0; g < 2; ++g)
      #pragma unroll
      for (int r = 0; r < 4; ++r) {
        const float inv = 1.0f / o[g][8][r];
        const long qr = wqb + g * 16 + quad * 4 + r;
        #pragma unroll
        for (int dt = 0; dt < 8; ++dt)
          Cp[qr * HID + dt * 16 + l16] = f2bf(o[g][dt][r] * inv);
      }
  }
}

// ---------------------------------------------------------------------------
extern "C" void kernel_launch(void* const* d_in, const int* in_sizes, int n_in,
                              void* d_out, int out_size, void* d_ws, size_t ws_size,
                              hipStream_t stream) {
  const float* X  = (const float*)d_in[0];
  const float* wq = (const float*)d_in[1];
  const float* bq = (const float*)d_in[2];
  const float* wk = (const float*)d_in[3];
  const float* bk = (const float*)d_in[4];
  const float* wv = (const float*)d_in[5];
  const float* bv = (const float*)d_in[6];
  const float* wo = (const float*)d_in[7];
  const float* bo = (const float*)d_in[8];
  float* out = (float*)d_out;

  const long HSZ = 4096L * 2048;   // B*S x H
  const long WSZ = 2048L * 2048;
  // ws (bf16 elems): Qw Kw Vw (3x16.8MB) + Xb (16.8MB) + W0..W2 (3x8.4MB)
  u16* Qw = (u16*)d_ws;
  u16* Kw = Qw + HSZ;
  u16* Vw = Kw + HSZ;
  u16* Xb = Vw + HSZ;
  u16* Wb = Xb + HSZ;              // W0,W1,W2 contiguous after Xb
  u16* W0 = Wb;

  dim3 blk(256);
  // one fused conversion: X (2 segs) + wq + wk + wv into Xb..W2 (contiguous)
  conv5_f32_bf16<<<dim3((int)(WSZ / 2048), 5), blk, 0, stream>>>(X, wq, wk, wv, Xb, WSZ);

  // fused Q/K/V projections: M=4096, N=6144, K=2048. Grid 512 = 2 rounds.
  gemm_bal<6, false><<<dim3(512), dim3(512), 0, stream>>>(
      Xb, Wb, bq, bk, bv, Qw, 2048, 64);

  // causal flash attention (balanced heavy+light pairs); ctx in-place over Qw
  attn_fwd<<<dim3(8, 32), blk, 0, stream>>>(Qw, Kw, Vw, Qw);

  // output projection (fp32 out): BN=256 -> grid 256 = exactly 1 block/CU.
  conv_f32_bf16<<<(int)(WSZ / 2048), blk, 0, stream>>>(wo, W0, WSZ);
  gemm_bal<4, true><<<dim3(256), dim3(512), 0, stream>>>(
      Qw, W0, bo, bo, bo, out, 2048, 32);
}

// Round 9
// 392.576 us; speedup vs baseline: 1.0086x; 1.0046x over previous
//
#include <hip/hip_runtime.h>
#include <stdint.h>

typedef unsigned short u16;
typedef __attribute__((ext_vector_type(8))) short short8;
typedef __attribute__((ext_vector_type(4))) short short4v;
typedef __attribute__((ext_vector_type(4))) float float4v;

union V8u { short8 v; short4v h[2]; u16 u[8]; unsigned w[4]; };

__device__ __forceinline__ u16 f2bf(float f) {
  unsigned u = __float_as_uint(f);
  u = u + 0x7FFFu + ((u >> 16) & 1u);   // round-to-nearest-even
  return (u16)(u >> 16);
}
__device__ __forceinline__ float4v fzero() {
  float4v z = {0.f, 0.f, 0.f, 0.f};
  return z;
}
__device__ __forceinline__ void gl_lds16(const u16* g, u16* l) {
  __builtin_amdgcn_global_load_lds(
      (const __attribute__((address_space(1))) void*)g,
      (__attribute__((address_space(3))) void*)l, 16, 0, 0);
}

#define MFMA16(a, b, c) __builtin_amdgcn_mfma_f32_16x16x32_bf16((a), (b), (c), 0, 0, 0)

// ---------------------------------------------------------------------------
// fp32 -> bf16 for 5 contiguous segments: X (2 segs) + wq,wk,wv. 8 elems/thr.
// ---------------------------------------------------------------------------
__global__ void conv5_f32_bf16(const float* __restrict__ X,
                               const float* __restrict__ w0,
                               const float* __restrict__ w1,
                               const float* __restrict__ w2,
                               u16* __restrict__ dst, long seg) {
  const int y = blockIdx.y;
  const float* s = (y < 2) ? (X + (long)y * seg)
                           : (y == 2 ? w0 : (y == 3 ? w1 : w2));
  u16* d = dst + (long)y * seg;
  const long i = ((long)blockIdx.x * 256 + threadIdx.x) * 8;
  if (i >= seg) return;
  float4 a = *(const float4*)&s[i];
  float4 b = *(const float4*)&s[i + 4];
  V8u o;
  o.u[0] = f2bf(a.x); o.u[1] = f2bf(a.y); o.u[2] = f2bf(a.z); o.u[3] = f2bf(a.w);
  o.u[4] = f2bf(b.x); o.u[5] = f2bf(b.y); o.u[6] = f2bf(b.z); o.u[7] = f2bf(b.w);
  *(short8*)&d[i] = o.v;
}

__global__ void conv_f32_bf16(const float* __restrict__ in, u16* __restrict__ out, long n) {
  const long i = ((long)blockIdx.x * 256 + threadIdx.x) * 8;
  if (i >= n) return;
  float4 a = *(const float4*)&in[i];
  float4 b = *(const float4*)&in[i + 4];
  V8u o;
  o.u[0] = f2bf(a.x); o.u[1] = f2bf(a.y); o.u[2] = f2bf(a.z); o.u[3] = f2bf(a.w);
  o.u[4] = f2bf(b.x); o.u[5] = f2bf(b.y); o.u[6] = f2bf(b.z); o.u[7] = f2bf(b.w);
  *(short8*)&out[i] = o.v;
}

// ---------------------------------------------------------------------------
// Balanced GEMM — FROZEN at the best-measured schedule (R5-form, 115.2-115.4us
// = 896 TF; fine-phase (R8) and 2-phase (R4) variants both measured worse).
// BM=128, BN=64*NREP, BK=64, 512 thr / 8 waves (2M x 4N).
//   QKV: NREP=6 (BN=384): grid 512 = exactly 2 balanced rounds.
//   OP:  NREP=4 (BN=256): grid 256 = exactly 1 block/CU.
// ---------------------------------------------------------------------------
template <int NREP, bool OUTF32>
__global__ __launch_bounds__(512, 2) void gemm_bal(
    const u16* __restrict__ X, const u16* __restrict__ Wb,
    const float* __restrict__ b0, const float* __restrict__ b1,
    const float* __restrict__ b2, void* __restrict__ Out,
    int K, int cpx)
{
  constexpr int NH = NREP / 2;
  __shared__ __align__(16) u16 lds[2][(2 + NREP) * 4096];

  const int t = threadIdx.x;            // 0..511
  const int lane = t & 63;
  const int wave = t >> 6;              // 0..7
  const int quad = lane >> 4, l16 = lane & 15;
  const int wm = wave >> 2, wn = wave & 3;   // 2 x 4 wave grid

  const int bid = (int)blockIdx.x;
  const int swz = (bid & 7) * cpx + (bid >> 3);
  const int by = swz & 31;              // 32 M-tiles of 128
  const int bx = swz >> 5;              // N-tiles of 64*NREP
  const long m0 = (long)by * 128;
  const long n0 = (long)bx * (64 * NREP);

  const u16* pA[2];
  #pragma unroll
  for (int l = 0; l < 2; ++l) {
    const int d = l * 8192 + t * 16;
    const int o = d ^ ((d >> 3) & 0x70);
    pA[l] = X + (m0 + (o >> 7)) * (long)K + ((o & 127) >> 1);
  }
  const u16* pB[NREP];
  #pragma unroll
  for (int s = 0; s < NREP; ++s) {
    const int d = s * 8192 + t * 16;
    const int o = d ^ ((d >> 3) & 0x70);
    pB[s] = Wb + (n0 + (o >> 7)) * (long)K + ((o & 127) >> 1);
  }

  int offk[2];
  #pragma unroll
  for (int kk = 0; kk < 2; ++kk)
    offk[kk] = l16 * 128 + ((kk * 64 + quad * 16) ^ ((l16 & 7) << 4));

  float4v acc[4][NREP];
  #pragma unroll
  for (int i = 0; i < 4; ++i)
    #pragma unroll
    for (int j = 0; j < NREP; ++j) acc[i][j] = fzero();

  auto STAGE = [&](u16* Lb, int kt_) {
    #pragma unroll
    for (int l = 0; l < 2; ++l)
      gl_lds16(pA[l] + (long)kt_ * 64, Lb + l * 4096 + t * 8);
    #pragma unroll
    for (int s = 0; s < NREP; ++s)
      gl_lds16(pB[s] + (long)kt_ * 64, Lb + 8192 + s * 4096 + t * 8);
  };

#define SB() __builtin_amdgcn_sched_barrier(0)
#define BAR() do { asm volatile("s_barrier" ::: "memory"); SB(); } while (0)

  const int NT = K >> 6;   // 32 K-tiles of 64

  STAGE(&lds[0][0], 0);
  asm volatile("s_waitcnt vmcnt(0)" ::: "memory");
  BAR();

  for (int kt = 0; kt < NT; ++kt) {
    const int buf = kt & 1;
    const int nkt = (kt + 1 < NT) ? kt + 1 : NT - 1;
    const char* Ab = (const char*)&lds[buf][0] + wm * 8192;
    const char* Bb = (const char*)&lds[buf][8192] + wn * (16 * NREP) * 128;

    short8 a[4][2], b[NREP][2];

    STAGE(&lds[buf ^ 1][0], nkt);

    #pragma unroll
    for (int i = 0; i < 4; ++i)
      a[i][0] = *(const short8*)(Ab + i * 2048 + offk[0]);
    #pragma unroll
    for (int j = 0; j < NH; ++j)
      b[j][0] = *(const short8*)(Bb + j * 2048 + offk[0]);
    #pragma unroll
    for (int j = NH; j < NREP; ++j)
      b[j][0] = *(const short8*)(Bb + j * 2048 + offk[0]);
    #pragma unroll
    for (int i = 0; i < 4; ++i)
      a[i][1] = *(const short8*)(Ab + i * 2048 + offk[1]);
    SB();

    __builtin_amdgcn_s_setprio(1);
    #pragma unroll
    for (int i = 0; i < 4; ++i)
      #pragma unroll
      for (int j = 0; j < NH; ++j)
        acc[i][j] = MFMA16(a[i][0], b[j][0], acc[i][j]);
    __builtin_amdgcn_s_setprio(0);
    SB();

    #pragma unroll
    for (int j = 0; j < NH; ++j)
      b[j][1] = *(const short8*)(Bb + j * 2048 + offk[1]);
    SB();

    __builtin_amdgcn_s_setprio(1);
    #pragma unroll
    for (int i = 0; i < 4; ++i)
      #pragma unroll
      for (int j = NH; j < NREP; ++j)
        acc[i][j] = MFMA16(a[i][0], b[j][0], acc[i][j]);
    __builtin_amdgcn_s_setprio(0);
    SB();

    #pragma unroll
    for (int j = NH; j < NREP; ++j)
      b[j][1] = *(const short8*)(Bb + j * 2048 + offk[1]);
    SB();

    __builtin_amdgcn_s_setprio(1);
    #pragma unroll
    for (int i = 0; i < 4; ++i)
      #pragma unroll
      for (int j = 0; j < NH; ++j)
        acc[i][j] = MFMA16(a[i][1], b[j][1], acc[i][j]);
    __builtin_amdgcn_s_setprio(0);
    SB();

    __builtin_amdgcn_s_setprio(1);
    #pragma unroll
    for (int i = 0; i < 4; ++i)
      #pragma unroll
      for (int j = NH; j < NREP; ++j)
        acc[i][j] = MFMA16(a[i][1], b[j][1], acc[i][j]);
    __builtin_amdgcn_s_setprio(0);

    asm volatile("s_waitcnt vmcnt(0)" ::: "memory");
    BAR();
  }

#undef SB
#undef BAR

  #pragma unroll
  for (int j = 0; j < NREP; ++j) {
    const int cg = (int)n0 + wn * (16 * NREP) + j * 16 + l16;
    const int z = cg >> 11, col = cg & 2047;
    const float* Bp = (z == 0) ? b0 : (z == 1 ? b1 : b2);
    const float bvv = Bp[col];
    #pragma unroll
    for (int i = 0; i < 4; ++i) {
      const long r0 = m0 + wm * 64 + i * 16 + quad * 4;
      #pragma unroll
      for (int r = 0; r < 4; ++r) {
        const long off = (long)z * (4096L * 2048) + (r0 + r) * 2048 + col;
        const float v = acc[i][j][r] + bvv;
        if (OUTF32) ((float*)Out)[off] = v;
        else        ((u16*)Out)[off] = f2bf(v);
      }
    }
  }
}

// ---------------------------------------------------------------------------
// Causal flash attention — dual-tile 8-wave blocks (2 waves/SIMD INSIDE one
// block; no cross-block co-residency presumption, unlike the failed R6 TLP).
// grid (8,32) = 256 blocks = 1 block/CU guaranteed; 512 thr / 8 waves.
// Each wave owns TWO 16-row groups from different Q-tiles:
//   group 0: heavy tile (15-x), rows rg0 = (15-x)*128 + wave*16
//   group 1: light tile (x),    rows rg1 = x*128     + wave*16   (rg1 < rg0)
// Per-group math (masks, fixed-scale softmax, Ps layout, Vt packing,
// ones-column row-sum) is byte-identical to the verified 4-wave kernel;
// only row bases differ. Both waves of a SIMD stay active through ALL
// iterations via their heavy groups -> the serial QK^T->exp->P-roundtrip->PV
// chain overlaps across the 2 waves (was fully exposed at 1 wave/SIMD).
// Work unchanged: light group branch-skipped once kv0 > rg1.
// Staging: threads 0..255 stage the 32 K rows, 256..511 the 32 V rows.
// In-place Ctx-over-Qw safe: block reads all its Q rows upfront; Ctx writes
// (its own rows only) happen after; K/V buffers are never written.
// ---------------------------------------------------------------------------
#define S_LEN 2048
#define HID   2048
#define HD    128

__global__ __launch_bounds__(512, 1) void attn_fwd(
    const u16* __restrict__ Q, const u16* __restrict__ K,
    const u16* __restrict__ V, u16* __restrict__ Ctx)
{
  __shared__ u16 Ks[2][32 * 136];      // K rows natural, pad 8
  __shared__ unsigned Vt[2][128 * 17]; // Vt[c][r/2] = V[2r'][c] | V[2r'+1][c]<<16
  __shared__ u16 Ps[8][2][512];        // per-wave, per-group P round-trip

  const int t = threadIdx.x;           // 0..511
  const int lane = t & 63, wave = t >> 6;   // wave 0..7
  const int quad = lane >> 4, l16 = lane & 15;
  const int x = (int)blockIdx.x;       // 0..7
  const int b = blockIdx.y >> 4, h = blockIdx.y & 15;

  const int hb = (15 - x) * 128;       // heavy tile base (1024..1920)
  const int lb = x * 128;              // light tile base (0..896)
  const int rg0 = hb + wave * 16;      // group-0 rows
  const int rg1 = lb + wave * 16;      // group-1 rows

  const long base = (long)b * S_LEN * HID + (long)h * HD;
  const u16* Qp = Q + base;
  const u16* Kp = K + base;
  const u16* Vp = V + base;
  u16* Cp = Ctx + base;

  // Q fragments for both groups (A-layout: m=lane&15, k=quad*8+j)
  short8 qf[2][4];
  #pragma unroll
  for (int g = 0; g < 2; ++g) {
    const long qr = (g ? rg1 : rg0) + l16;
    #pragma unroll
    for (int kk = 0; kk < 4; ++kk)
      qf[g][kk] = *(const short8*)&Qp[qr * HID + kk * 32 + quad * 8];
  }

  short8 onesv;
  {
    V8u ou;
    #pragma unroll
    for (int j = 0; j < 8; ++j) ou.u[j] = 0x3F80;   // bf16 1.0
    onesv = ou.v;
  }
  const float SC = 0.08838834764831845f * 1.4426950408889634f; // scale*log2e

  float4v o[2][9];                 // per group: [0..7] d-groups, [8] row-sum
  #pragma unroll
  for (int g = 0; g < 2; ++g)
    #pragma unroll
    for (int i = 0; i < 9; ++i) o[g][i] = fzero();

  // staging: half the threads do K, half do V; 2 rows (b128 each) per thread
  const int st = t & 255;
  const int sr2 = st >> 4;             // 0..15 row-pair
  const int sc8 = (st & 15) * 8;       // feature col base
  const bool isV = t >= 256;
  const u16* Sp = isV ? Vp : Kp;

  short8 r0, r1;
  auto LOADKV = [&](int row0) {
    const long g0 = (long)(row0 + 2 * sr2) * HID + sc8;
    r0 = *(const short8*)&Sp[g0];
    r1 = *(const short8*)&Sp[g0 + HID];
  };
  auto COMMIT = [&](int pb) {
    if (!isV) {
      *(short8*)&Ks[pb][(2 * sr2) * 136 + sc8]     = r0;
      *(short8*)&Ks[pb][(2 * sr2 + 1) * 136 + sc8] = r1;
    } else {
      V8u a, c; a.v = r0; c.v = r1;
      #pragma unroll
      for (int j = 0; j < 8; ++j)
        Vt[pb][(sc8 + j) * 17 + sr2] = (unsigned)a.u[j] | ((unsigned)c.u[j] << 16);
    }
  };

  LOADKV(0);
  COMMIT(0);
  __syncthreads();

  const int T = (hb + 128) >> 5;   // KV tiles for the heavy tile (max need)
  for (int ti = 0; ti < T; ++ti) {
    const int kv0 = ti << 5;
    const int p = ti & 1;

    const bool more = (ti + 1 < T);
    if (more) LOADKV(kv0 + 32);

    if (kv0 <= rg0) {                   // wave-uniform (16-row groups, kv0 32-aligned: kv0<=rg0+15 <=> kv0<=rg0)
      const bool act1 = kv0 <= rg1;     // light group still active?
      if (act1) {
        // ---- both groups (kf/vf read once, used twice) ----
        float4v s[2][2];
        #pragma unroll
        for (int g = 0; g < 2; ++g) { s[g][0] = fzero(); s[g][1] = fzero(); }
        #pragma unroll
        for (int ni = 0; ni < 2; ++ni)
          #pragma unroll
          for (int kk = 0; kk < 4; ++kk) {
            short8 kf = *(const short8*)&Ks[p][(ni * 16 + l16) * 136 + kk * 32 + quad * 8];
            s[0][ni] = MFMA16(qf[0][kk], kf, s[0][ni]);
            s[1][ni] = MFMA16(qf[1][kk], kf, s[1][ni]);
          }
        #pragma unroll
        for (int g = 0; g < 2; ++g) {
          const int qrow0 = (g ? rg1 : rg0) + quad * 4;
          #pragma unroll
          for (int r = 0; r < 4; ++r) {
            float s0 = fminf(s[g][0][r] * SC, 80.f);
            float s1 = fminf(s[g][1][r] * SC, 80.f);
            if (kv0 + l16 > qrow0 + r)      s0 = -1e30f;
            if (kv0 + 16 + l16 > qrow0 + r) s1 = -1e30f;
            Ps[wave][g][(quad * 4 + r) * 32 + l16]      = f2bf(__builtin_amdgcn_exp2f(s0));
            Ps[wave][g][(quad * 4 + r) * 32 + 16 + l16] = f2bf(__builtin_amdgcn_exp2f(s1));
          }
        }
        __threadfence_block();
        short8 pf0 = *(const short8*)&Ps[wave][0][l16 * 32 + quad * 8];
        short8 pf1 = *(const short8*)&Ps[wave][1][l16 * 32 + quad * 8];

        #pragma unroll
        for (int dt = 0; dt < 8; ++dt) {
          const unsigned* vp = &Vt[p][(dt * 16 + l16) * 17 + quad * 4];
          V8u vf;
          vf.w[0] = vp[0]; vf.w[1] = vp[1]; vf.w[2] = vp[2]; vf.w[3] = vp[3];
          o[0][dt] = MFMA16(pf0, vf.v, o[0][dt]);
          o[1][dt] = MFMA16(pf1, vf.v, o[1][dt]);
        }
        o[0][8] = MFMA16(pf0, onesv, o[0][8]);
        o[1][8] = MFMA16(pf1, onesv, o[1][8]);
      } else {
        // ---- heavy group only ----
        float4v s0v[2] = {fzero(), fzero()};
        #pragma unroll
        for (int ni = 0; ni < 2; ++ni)
          #pragma unroll
          for (int kk = 0; kk < 4; ++kk) {
            short8 kf = *(const short8*)&Ks[p][(ni * 16 + l16) * 136 + kk * 32 + quad * 8];
            s0v[ni] = MFMA16(qf[0][kk], kf, s0v[ni]);
          }
        {
          const int qrow0 = rg0 + quad * 4;
          #pragma unroll
          for (int r = 0; r < 4; ++r) {
            float s0 = fminf(s0v[0][r] * SC, 80.f);
            float s1 = fminf(s0v[1][r] * SC, 80.f);
            if (kv0 + l16 > qrow0 + r)      s0 = -1e30f;
            if (kv0 + 16 + l16 > qrow0 + r) s1 = -1e30f;
            Ps[wave][0][(quad * 4 + r) * 32 + l16]      = f2bf(__builtin_amdgcn_exp2f(s0));
            Ps[wave][0][(quad * 4 + r) * 32 + 16 + l16] = f2bf(__builtin_amdgcn_exp2f(s1));
          }
        }
        __threadfence_block();
        short8 pf0 = *(const short8*)&Ps[wave][0][l16 * 32 + quad * 8];

        #pragma unroll
        for (int dt = 0; dt < 8; ++dt) {
          const unsigned* vp = &Vt[p][(dt * 16 + l16) * 17 + quad * 4];
          V8u vf;
          vf.w[0] = vp[0]; vf.w[1] = vp[1]; vf.w[2] = vp[2]; vf.w[3] = vp[3];
          o[0][dt] = MFMA16(pf0, vf.v, o[0][dt]);
        }
        o[0][8] = MFMA16(pf0, onesv, o[0][8]);
      }
    }

    if (more) COMMIT(1 - p);
    __syncthreads();
  }

  // ---- epilogue: O / L -> ctx (merged-head layout [B*S][H]) ----
  #pragma unroll
  for (int g = 0; g < 2; ++g)
    #pragma unroll
    for (int r = 0; r < 4; ++r) {
      const float inv = 1.0f / o[g][8][r];
      const long qr = (g ? rg1 : rg0) + quad * 4 + r;
      #pragma unroll
      for (int dt = 0; dt < 8; ++dt)
        Cp[qr * HID + dt * 16 + l16] = f2bf(o[g][dt][r] * inv);
    }
}

// ---------------------------------------------------------------------------
extern "C" void kernel_launch(void* const* d_in, const int* in_sizes, int n_in,
                              void* d_out, int out_size, void* d_ws, size_t ws_size,
                              hipStream_t stream) {
  const float* X  = (const float*)d_in[0];
  const float* wq = (const float*)d_in[1];
  const float* bq = (const float*)d_in[2];
  const float* wk = (const float*)d_in[3];
  const float* bk = (const float*)d_in[4];
  const float* wv = (const float*)d_in[5];
  const float* bv = (const float*)d_in[6];
  const float* wo = (const float*)d_in[7];
  const float* bo = (const float*)d_in[8];
  float* out = (float*)d_out;

  const long HSZ = 4096L * 2048;   // B*S x H
  const long WSZ = 2048L * 2048;
  // ws (bf16 elems): Qw Kw Vw (3x16.8MB) + Xb (16.8MB) + W0..W2 (3x8.4MB)
  u16* Qw = (u16*)d_ws;
  u16* Kw = Qw + HSZ;
  u16* Vw = Kw + HSZ;
  u16* Xb = Vw + HSZ;
  u16* Wb = Xb + HSZ;              // W0,W1,W2 contiguous after Xb
  u16* W0 = Wb;

  dim3 blk(256);
  // one fused conversion: X (2 segs) + wq + wk + wv into Xb..W2 (contiguous)
  conv5_f32_bf16<<<dim3((int)(WSZ / 2048), 5), blk, 0, stream>>>(X, wq, wk, wv, Xb, WSZ);

  // fused Q/K/V projections: M=4096, N=6144, K=2048. Grid 512 = 2 rounds.
  gemm_bal<6, false><<<dim3(512), dim3(512), 0, stream>>>(
      Xb, Wb, bq, bk, bv, Qw, 2048, 64);

  // causal flash attention: dual-tile 8-wave blocks, 1 block/CU,
  // 2 waves/SIMD; ctx in-place over Qw.
  attn_fwd<<<dim3(8, 32), dim3(512), 0, stream>>>(Qw, Kw, Vw, Qw);

  // output projection (fp32 out): BN=256 -> grid 256 = exactly 1 block/CU.
  conv_f32_bf16<<<(int)(WSZ / 2048), blk, 0, stream>>>(wo, W0, WSZ);
  gemm_bal<4, true><<<dim3(256), dim3(512), 0, stream>>>(
      Qw, W0, bo, bo, bo, out, 2048, 32);
}